// Round 2
// baseline (294.798 us; speedup 1.0000x reference)
//
#include <hip/hip_runtime.h>
#include <math.h>

#define DIM     512
#define NPROTO  64
#define TR      128       // query rows per block (kernel A)
#define NCH     8         // K chunks (each khalf stages 32 ks per chunk)

// workspace layout
#define WS_PROTOT   0          // float[512][64]            (128 KiB)
#define WS_INV64    131072     // double[64]                (512 B)
#define WS_FLAGS    131584     // int[65536]                (256 KiB)

// ---------------------------------------------------------------------------
// Kernel 1: fp64-normalize prototypes -> protoT[k][p] fp32, inv64[p] fp64.
// ---------------------------------------------------------------------------
__global__ __launch_bounds__(256) void prep_protos_kernel(
    const float* __restrict__ protos, float* __restrict__ protoT,
    double* __restrict__ inv64) {
  const int p = (blockIdx.x * blockDim.x + threadIdx.x) >> 6;
  const int lane = threadIdx.x & 63;
  if (p >= NPROTO) return;
  const float4* pr = (const float4*)(protos + (size_t)p * DIM);
  const float4 a = pr[lane * 2];
  const float4 b = pr[lane * 2 + 1];
  double ss = (double)a.x * a.x + (double)a.y * a.y + (double)a.z * a.z +
              (double)a.w * a.w + (double)b.x * b.x + (double)b.y * b.y +
              (double)b.z * b.z + (double)b.w * b.w;
#pragma unroll
  for (int m = 1; m < 64; m <<= 1) ss += __shfl_xor(ss, m);
  const double inv = 1.0 / fmax(sqrt(ss), 1e-12);
  if (lane == 0) inv64[p] = inv;
  const float v[8] = {a.x, a.y, a.z, a.w, b.x, b.y, b.z, b.w};
#pragma unroll
  for (int e = 0; e < 8; ++e)
    protoT[(size_t)(lane * 8 + e) * NPROTO + p] = (float)((double)v[e] * inv);
}

// ---------------------------------------------------------------------------
// Kernel 2 (A): fp32 sims via lane=row / SGPR-broadcast protos.
// 512 threads = 8 waves: (rgroup 0-1) x (proto-half 0-1) x (K-half 0-1).
// Each lane owns one query row; 32 fp32 accumulators = 32 protos.
// Top-4 scan in registers; near-tie rows flagged for fp64 refine.
// ---------------------------------------------------------------------------
__global__ __launch_bounds__(512) void sim_kernel(
    const float* __restrict__ query, const float* __restrict__ protos,
    const float* __restrict__ protoT, float* __restrict__ out,
    int* __restrict__ flags) {
  // LDS: Astage [2][128][36] floats (9216) | sims overlay [128][68] (8704)
  //      nred [2][128][8] (2048) @9216 | wiS float4[128] @11264 | qiS[128] @11776
  __shared__ float smem[11904];
  float* Ast = smem;
  float* sims = smem;
  float* nred = smem + 9216;
  float4* wiS = (float4*)(smem + 11264);
  float* qiS = smem + 11776;

  const int t = threadIdx.x;
  const int lane = t & 63;
  const int wid = t >> 6;
  const int rg = __builtin_amdgcn_readfirstlane(wid & 1);
  const int ph = __builtin_amdgcn_readfirstlane((wid >> 1) & 1);
  const int kh = __builtin_amdgcn_readfirstlane(wid >> 2);
  const int myrow = rg * 64 + lane;
  const int row0 = blockIdx.x * TR;

  // staging piece mapping: 4 pieces per thread, g = s*512 + t
  const float* gsrc[4];
  int loff[4], noff[4];
#pragma unroll
  for (int s = 0; s < 4; ++s) {
    const int g = s * 512 + t;
    const int W = g >> 10;
    const int r = (g >> 3) & 127;
    const int pc = g & 7;
    gsrc[s] = query + (size_t)(row0 + r) * DIM + W * 256 + pc * 4;
    loff[s] = (W * 128 + r) * 36 + pc * 4;
    noff[s] = (W * 128 + r) * 8 + pc;
  }

  float acc[32];
#pragma unroll
  for (int i = 0; i < 32; ++i) acc[i] = 0.0f;
  float na[4] = {0.f, 0.f, 0.f, 0.f};

  for (int c = 0; c < NCH; ++c) {
    float4 st[4];
#pragma unroll
    for (int s = 0; s < 4; ++s) st[s] = *(const float4*)(gsrc[s] + c * 32);
    __syncthreads();
#pragma unroll
    for (int s = 0; s < 4; ++s) {
      *(float4*)&Ast[loff[s]] = st[s];
      na[s] += st[s].x * st[s].x + st[s].y * st[s].y + st[s].z * st[s].z +
               st[s].w * st[s].w;
    }
    __syncthreads();
    const float* arow = &Ast[(kh * 128 + myrow) * 36];
    const float* pbase = protoT + (size_t)(kh * 256 + c * 32) * NPROTO + ph * 32;
#pragma unroll
    for (int g = 0; g < 8; ++g) {
      const float4 a4 = *(const float4*)(arow + g * 4);
      const float av[4] = {a4.x, a4.y, a4.z, a4.w};
#pragma unroll
      for (int u = 0; u < 4; ++u) {
        const float* pk = pbase + (g * 4 + u) * NPROTO;
#pragma unroll
        for (int p4 = 0; p4 < 8; ++p4) {
          const float4 pv = *(const float4*)(pk + p4 * 4);
          acc[p4 * 4 + 0] = fmaf(pv.x, av[u], acc[p4 * 4 + 0]);
          acc[p4 * 4 + 1] = fmaf(pv.y, av[u], acc[p4 * 4 + 1]);
          acc[p4 * 4 + 2] = fmaf(pv.z, av[u], acc[p4 * 4 + 2]);
          acc[p4 * 4 + 3] = fmaf(pv.w, av[u], acc[p4 * 4 + 3]);
        }
      }
    }
  }

  // norm partials
#pragma unroll
  for (int s = 0; s < 4; ++s) nred[noff[s]] = na[s];
  __syncthreads();

  // K-half 1 dumps acc into sims (overlays Astage); waves 4,5 compute qinv
  if (kh == 1) {
    float* srow = &sims[myrow * 68 + ph * 32];
#pragma unroll
    for (int p4 = 0; p4 < 8; ++p4) {
      float4 v = make_float4(acc[p4 * 4 + 0], acc[p4 * 4 + 1],
                             acc[p4 * 4 + 2], acc[p4 * 4 + 3]);
      *(float4*)&srow[p4 * 4] = v;
    }
    if (wid == 4 || wid == 5) {
      const int r = (wid - 4) * 64 + lane;
      float s = 0.f;
#pragma unroll
      for (int i = 0; i < 2; ++i) {
        const float4 x = *(const float4*)&nred[(i * 128 + r) * 8];
        const float4 y = *(const float4*)&nred[(i * 128 + r) * 8 + 4];
        s += x.x + x.y + x.z + x.w + y.x + y.y + y.z + y.w;
      }
      qiS[r] = (float)(1.0 / fmax(sqrt((double)s), 1e-12));
    }
  }
  __syncthreads();

  if (kh == 0) {  // combine K-halves
    const float* srow = &sims[myrow * 68 + ph * 32];
#pragma unroll
    for (int p4 = 0; p4 < 8; ++p4) {
      const float4 v = *(const float4*)&srow[p4 * 4];
      acc[p4 * 4 + 0] += v.x;
      acc[p4 * 4 + 1] += v.y;
      acc[p4 * 4 + 2] += v.z;
      acc[p4 * 4 + 3] += v.w;
    }
  }
  __syncthreads();

  if (kh == 0 && ph == 1) {  // publish upper proto half
    float* srow = &sims[myrow * 68 + 32];
#pragma unroll
    for (int p4 = 0; p4 < 8; ++p4) {
      float4 v = make_float4(acc[p4 * 4 + 0], acc[p4 * 4 + 1],
                             acc[p4 * 4 + 2], acc[p4 * 4 + 3]);
      *(float4*)&srow[p4 * 4] = v;
    }
  }
  __syncthreads();

  if (kh == 0 && ph == 0) {  // scan 64 sims, softmax, flag
    float ob[32];
    const float* srow = &sims[myrow * 68 + 32];
#pragma unroll
    for (int p4 = 0; p4 < 8; ++p4) {
      const float4 v = *(const float4*)&srow[p4 * 4];
      ob[p4 * 4 + 0] = v.x; ob[p4 * 4 + 1] = v.y;
      ob[p4 * 4 + 2] = v.z; ob[p4 * 4 + 3] = v.w;
    }
    float v1 = -1e30f, v2 = -1e30f, v3 = -1e30f, v4 = -1e30f;
    int i1 = 0, i2 = 0, i3 = 0, i4 = 0;
#pragma unroll
    for (int j = 0; j < 64; ++j) {
      const float v = (j < 32) ? acc[j] : ob[j - 32];
      const bool b1 = v > v1, b2 = v > v2, b3 = v > v3, b4 = v > v4;
      v4 = b4 ? (b3 ? v3 : v) : v4;  i4 = b4 ? (b3 ? i3 : j) : i4;
      v3 = b3 ? (b2 ? v2 : v) : v3;  i3 = b3 ? (b2 ? i2 : j) : i3;
      v2 = b2 ? (b1 ? v1 : v) : v2;  i2 = b2 ? (b1 ? i1 : j) : i2;
      v1 = b1 ? v : v1;              i1 = b1 ? j : i1;
    }
    const float qi = qiS[myrow];
    const float s1 = v1 * qi, s2 = v2 * qi, s3 = v3 * qi, s4 = v4 * qi;
    const float e2 = expf(s2 - s1);
    const float e3 = expf(s3 - s1);
    const float inv = 1.0f / (1.0f + e2 + e3);
    const int pack = i1 | (i2 << 6) | (i3 << 12);
    wiS[myrow] = make_float4(inv, e2 * inv, e3 * inv, __int_as_float(pack));
    flags[row0 + myrow] = (s3 - s4 < 1e-4f) ? 1 : 0;
  }
  __syncthreads();

  // epilogue: wave w -> rows it*4 + (w>>1), column half (w&1); fully coalesced
  const int half = wid & 1;
  const int rsub = wid >> 1;
#pragma unroll 4
  for (int it = 0; it < 32; ++it) {
    const int r = it * 4 + rsub;
    const float4 wi = wiS[r];
    const int pack = __float_as_int(wi.w);
    const int i0 = pack & 63, i1 = (pack >> 6) & 63, i2 = (pack >> 12) & 63;
    const float4 a = ((const float4*)(protos + (size_t)i0 * DIM + half * 256))[lane];
    const float4 b = ((const float4*)(protos + (size_t)i1 * DIM + half * 256))[lane];
    const float4 cc = ((const float4*)(protos + (size_t)i2 * DIM + half * 256))[lane];
    float4 res;
    res.x = wi.x * a.x + wi.y * b.x + wi.z * cc.x;
    res.y = wi.x * a.y + wi.y * b.y + wi.z * cc.y;
    res.z = wi.x * a.z + wi.y * b.z + wi.z * cc.z;
    res.w = wi.x * a.w + wi.y * b.w + wi.z * cc.w;
    ((float4*)(out + (size_t)(row0 + r) * DIM + half * 256))[lane] = res;
  }
}

// ---------------------------------------------------------------------------
// Kernel 3 (B): fp64 refine of flagged (near-tie) rows. 256 thr; block b
// handles rows [b*256, b*256+256).
// ---------------------------------------------------------------------------
__global__ __launch_bounds__(256) void refine_kernel(
    const float* __restrict__ query, const float* __restrict__ protos,
    const double* __restrict__ inv64, const int* __restrict__ flags,
    float* __restrict__ out) {
  __shared__ int fL[256];
  __shared__ double simsL[NPROTO];
  __shared__ double wL[3];
  __shared__ int iL[3];
  const int t = threadIdx.x;
  const int rbase = blockIdx.x * 256;
  fL[t] = flags[rbase + t];
  __syncthreads();

  for (int j = 0; j < 256; ++j) {
    if (!fL[j]) continue;  // uniform branch (LDS value)
    const int row = rbase + j;
    const int p = t >> 2, c = t & 3;
    const float4* q4 = (const float4*)(query + (size_t)row * DIM + c * 128);
    const float4* p4 = (const float4*)(protos + (size_t)p * DIM + c * 128);
    double acc = 0.0, qs = 0.0;
    for (int i = 0; i < 32; ++i) {
      const float4 qv = q4[i];
      const float4 pv = p4[i];
      acc += (double)qv.x * pv.x + (double)qv.y * pv.y +
             (double)qv.z * pv.z + (double)qv.w * pv.w;
      if (p == 0)
        qs += (double)qv.x * qv.x + (double)qv.y * qv.y +
              (double)qv.z * qv.z + (double)qv.w * qv.w;
    }
    acc += __shfl_xor(acc, 1);
    acc += __shfl_xor(acc, 2);
    if (c == 0) simsL[p] = acc * inv64[p];
    if (p == 0) { qs += __shfl_xor(qs, 1); qs += __shfl_xor(qs, 2); }
    __syncthreads();
    if (t == 0) {
      const double qi = 1.0 / fmax(sqrt(qs), 1e-12);
      double v1 = -1e300, v2 = -1e300, v3 = -1e300;
      int i1 = 0, i2 = 0, i3 = 0;
      for (int k = 0; k < NPROTO; ++k) {
        const double v = simsL[k];
        if (v > v1)      { v3 = v2; i3 = i2; v2 = v1; i2 = i1; v1 = v; i1 = k; }
        else if (v > v2) { v3 = v2; i3 = i2; v2 = v; i2 = k; }
        else if (v > v3) { v3 = v; i3 = k; }
      }
      const double s1 = v1 * qi, s2 = v2 * qi, s3 = v3 * qi;
      const double e2 = exp(s2 - s1), e3 = exp(s3 - s1);
      const double inv = 1.0 / (1.0 + e2 + e3);
      wL[0] = inv; wL[1] = e2 * inv; wL[2] = e3 * inv;
      iL[0] = i1; iL[1] = i2; iL[2] = i3;
    }
    __syncthreads();
    float* orow = out + (size_t)row * DIM;
    const double w0 = wL[0], w1 = wL[1], w2 = wL[2];
    const float* r0 = protos + (size_t)iL[0] * DIM;
    const float* r1 = protos + (size_t)iL[1] * DIM;
    const float* r2 = protos + (size_t)iL[2] * DIM;
#pragma unroll
    for (int e = 0; e < 2; ++e) {
      const int col = t * 2 + e;
      orow[col] = (float)(w0 * r0[col] + w1 * r1[col] + w2 * r2[col]);
    }
    __syncthreads();
  }
}

extern "C" void kernel_launch(void* const* d_in, const int* in_sizes, int n_in,
                              void* d_out, int out_size, void* d_ws, size_t ws_size,
                              hipStream_t stream) {
  const float* query = (const float*)d_in[0];
  const float* protos = (const float*)d_in[1];
  float* out = (float*)d_out;
  float* protoT = (float*)((char*)d_ws + WS_PROTOT);
  double* inv64 = (double*)((char*)d_ws + WS_INV64);
  int* flags = (int*)((char*)d_ws + WS_FLAGS);

  const int nrows = in_sizes[0] / DIM;

  hipLaunchKernelGGL(prep_protos_kernel, dim3(16), dim3(256), 0, stream,
                     protos, protoT, inv64);
  hipLaunchKernelGGL(sim_kernel, dim3(nrows / TR), dim3(512), 0, stream,
                     query, protos, protoT, out, flags);
  hipLaunchKernelGGL(refine_kernel, dim3(nrows / 256), dim3(256), 0, stream,
                     query, protos, inv64, flags, out);
}

// Round 3
// 133.128 us; speedup vs baseline: 2.2144x; 2.2144x over previous
//
#include <hip/hip_runtime.h>
#include <math.h>

#define DIM   512
#define NP    64
#define TRB   128           // query rows per block (sim kernel)
#define BK    32            // k per chunk
#define NCH   16            // chunks (512/32)
#define ASTR  132           // Ast stride in floats (128 + 4 pad)
#define TAU   1e-5f         // gap34 flag threshold (cosine units)
#define RFB   128           // refine blocks

// workspace layout (bytes)
#define WS_PTRAW 0          // float[512][64] raw transposed protos (131072)
#define WS_INV64 131072     // double[64]   (512)
#define WS_INVPF 131584     // float[64]    (256)
#define WS_CNT   131840     // int          (4)
#define WS_LIST  131968     // int[65536]   (262144)

// ---------------------------------------------------------------------------
// insert helpers (descending top-k with index tracking)
// ---------------------------------------------------------------------------
__device__ __forceinline__ void ins4f(float v, int idx, float& v0, float& v1,
                                      float& v2, float& v3, int& j0, int& j1,
                                      int& j2, int& j3) {
  const bool b0 = v > v0, b1 = v > v1, b2 = v > v2, b3 = v > v3;
  v3 = b2 ? v2 : (b3 ? v : v3);  j3 = b2 ? j2 : (b3 ? idx : j3);
  v2 = b1 ? v1 : (b2 ? v : v2);  j2 = b1 ? j1 : (b2 ? idx : j2);
  v1 = b0 ? v0 : (b1 ? v : v1);  j1 = b0 ? j0 : (b1 ? idx : j1);
  v0 = b0 ? v  : v0;             j0 = b0 ? idx : j0;
}

__device__ __forceinline__ void ins3d(double v, int idx, double& b0, double& b1,
                                      double& b2, int& k0, int& k1, int& k2) {
  const bool c0 = v > b0, c1 = v > b1, c2 = v > b2;
  b2 = c1 ? b1 : (c2 ? v : b2);  k2 = c1 ? k1 : (c2 ? idx : k2);
  b1 = c0 ? b0 : (c1 ? v : b1);  k1 = c0 ? k0 : (c1 ? idx : k1);
  b0 = c0 ? v  : b0;             k0 = c0 ? idx : k0;
}

// ---------------------------------------------------------------------------
// Kernel 1: raw-transpose protos -> ptw[k][p]; fp64 inverse norms; zero count.
// One wave per prototype (16 blocks x 256).
// ---------------------------------------------------------------------------
__global__ __launch_bounds__(256) void prep_kernel(
    const float* __restrict__ protos, float* __restrict__ ptw,
    double* __restrict__ inv64, float* __restrict__ invpf,
    int* __restrict__ cnt) {
  if (blockIdx.x == 0 && threadIdx.x == 0) *cnt = 0;
  const int p = (blockIdx.x * 256 + threadIdx.x) >> 6;
  const int lane = threadIdx.x & 63;
  if (p >= NP) return;
  const float4* pr = (const float4*)(protos + (size_t)p * DIM);
  const float4 a = pr[lane * 2];
  const float4 b = pr[lane * 2 + 1];
  double ss = (double)a.x * a.x + (double)a.y * a.y + (double)a.z * a.z +
              (double)a.w * a.w + (double)b.x * b.x + (double)b.y * b.y +
              (double)b.z * b.z + (double)b.w * b.w;
#pragma unroll
  for (int m = 1; m < 64; m <<= 1) ss += __shfl_xor(ss, m);
  const double inv = 1.0 / fmax(sqrt(ss), 1e-12);
  if (lane == 0) { inv64[p] = inv; invpf[p] = (float)inv; }
  const float v[8] = {a.x, a.y, a.z, a.w, b.x, b.y, b.z, b.w};
#pragma unroll
  for (int e = 0; e < 8; ++e)
    ptw[(size_t)(lane * 8 + e) * NP + p] = v[e];
}

// ---------------------------------------------------------------------------
// Kernel 2: fused fp32 sim GEMM -> in-register top4 -> softmax -> gather.
// 256 threads, 128 rows/block. Thread tile: 8 rows x 4 protos.
// ---------------------------------------------------------------------------
__global__ __launch_bounds__(256, 4) void sim_kernel(
    const float* __restrict__ query, const float* __restrict__ protos,
    const float* __restrict__ ptw, const float* __restrict__ invpf,
    float* __restrict__ out, int* __restrict__ cnt, int* __restrict__ list) {
  __shared__ float Ast[BK * ASTR];     // [k][row] transposed A tile
  __shared__ float Bst[BK * NP];       // [k][proto]
  __shared__ float nredL[TRB * 8];     // per-row sumsq partials
  __shared__ float qiS[TRB];           // per-row 1/|q|
  __shared__ float4 wiS[TRB];          // weights + packed indices

  const int t = threadIdx.x;
  const int row0 = blockIdx.x * TRB;
  const int tr = t >> 4;               // 0..15 -> rows tr*8..tr*8+7
  const int tp = t & 15;               // 0..15 -> protos tp*4..tp*4+3
  const int arow = t >> 3;             // staging: rows arow+32s
  const int acp = t & 7;               // staging: float4 col within 32-chunk

  const float* aptr[4];
#pragma unroll
  for (int s = 0; s < 4; ++s)
    aptr[s] = query + (size_t)(row0 + arow + 32 * s) * DIM + acp * 4;
  const float* bptr = ptw + t * 8;

  float acc[8][4] = {};
  float na[4] = {0.f, 0.f, 0.f, 0.f};

  float4 Ar[4], Br0, Br1;
#pragma unroll
  for (int s = 0; s < 4; ++s) Ar[s] = *(const float4*)(aptr[s]);
  Br0 = *(const float4*)(bptr);
  Br1 = *(const float4*)(bptr + 4);

  for (int c = 0; c < NCH; ++c) {
    __syncthreads();   // previous chunk's LDS reads complete
#pragma unroll
    for (int s = 0; s < 4; ++s) {
      const float v[4] = {Ar[s].x, Ar[s].y, Ar[s].z, Ar[s].w};
      const int rl = arow + 32 * s;
#pragma unroll
      for (int e = 0; e < 4; ++e) Ast[(acp * 4 + e) * ASTR + rl] = v[e];
      na[s] += v[0] * v[0] + v[1] * v[1] + v[2] * v[2] + v[3] * v[3];
    }
    *(float4*)&Bst[t * 8] = Br0;
    *(float4*)&Bst[t * 8 + 4] = Br1;
    __syncthreads();
    if (c + 1 < NCH) {
#pragma unroll
      for (int s = 0; s < 4; ++s)
        Ar[s] = *(const float4*)(aptr[s] + (c + 1) * BK);
      Br0 = *(const float4*)(bptr + (c + 1) * BK * NP);
      Br1 = *(const float4*)(bptr + (c + 1) * BK * NP + 4);
    }
#pragma unroll 8
    for (int kk = 0; kk < BK; ++kk) {
      const float4 a0 = *(const float4*)&Ast[kk * ASTR + tr * 8];
      const float4 a1 = *(const float4*)&Ast[kk * ASTR + tr * 8 + 4];
      const float4 b0 = *(const float4*)&Bst[kk * NP + tp * 4];
      const float av[8] = {a0.x, a0.y, a0.z, a0.w, a1.x, a1.y, a1.z, a1.w};
      const float bv[4] = {b0.x, b0.y, b0.z, b0.w};
#pragma unroll
      for (int i = 0; i < 8; ++i)
#pragma unroll
        for (int j = 0; j < 4; ++j)
          acc[i][j] = fmaf(av[i], bv[j], acc[i][j]);
    }
  }

  // per-row 1/|q|
#pragma unroll
  for (int s = 0; s < 4; ++s) nredL[(arow + 32 * s) * 8 + acp] = na[s];
  __syncthreads();
  if (t < TRB) {
    float ssum = 0.f;
#pragma unroll
    for (int e = 0; e < 8; ++e) ssum += nredL[t * 8 + e];
    qiS[t] = 1.0f / fmaxf(sqrtf(ssum), 1e-12f);
  }
  __syncthreads();

  // selection: per row, 16-lane shfl-merge of top-4 (value = dot * invp)
  const float4 ipv = *(const float4*)(invpf + tp * 4);
  const float ip[4] = {ipv.x, ipv.y, ipv.z, ipv.w};
#pragma unroll
  for (int i = 0; i < 8; ++i) {
    const int row = tr * 8 + i;
    float v0 = -1e30f, v1 = -1e30f, v2 = -1e30f, v3 = -1e30f;
    int j0 = 0, j1 = 0, j2 = 0, j3 = 0;
#pragma unroll
    for (int j = 0; j < 4; ++j)
      ins4f(acc[i][j] * ip[j], tp * 4 + j, v0, v1, v2, v3, j0, j1, j2, j3);
#pragma unroll
    for (int m = 1; m <= 8; m <<= 1) {
      const float p0 = __shfl_xor(v0, m), p1 = __shfl_xor(v1, m);
      const float p2 = __shfl_xor(v2, m), p3 = __shfl_xor(v3, m);
      const int q0 = __shfl_xor(j0, m), q1 = __shfl_xor(j1, m);
      const int q2 = __shfl_xor(j2, m), q3 = __shfl_xor(j3, m);
      ins4f(p0, q0, v0, v1, v2, v3, j0, j1, j2, j3);
      ins4f(p1, q1, v0, v1, v2, v3, j0, j1, j2, j3);
      ins4f(p2, q2, v0, v1, v2, v3, j0, j1, j2, j3);
      ins4f(p3, q3, v0, v1, v2, v3, j0, j1, j2, j3);
    }
    if (tp == 0) {
      const float qi = qiS[row];
      const float s0 = v0 * qi, s1 = v1 * qi, s2 = v2 * qi, s3 = v3 * qi;
      const float e1 = expf(s1 - s0), e2 = expf(s2 - s0);
      const float inv = 1.0f / (1.0f + e1 + e2);
      wiS[row] = make_float4(inv, e1 * inv, e2 * inv,
                             __int_as_float(j0 | (j1 << 6) | (j2 << 12)));
      if (s2 - s3 < TAU) {
        const int pos = atomicAdd(cnt, 1);
        list[pos] = row0 + row;
      }
    }
  }
  __syncthreads();

  // epilogue: (row, half) tasks, fully coalesced 1 KB stores
  const int wid = t >> 6;
  const int lane = t & 63;
#pragma unroll 4
  for (int it = 0; it < 64; ++it) {
    const int idx = it * 4 + wid;
    const int r = idx >> 1, h = idx & 1;
    const float4 wi = wiS[r];
    const int pack = __float_as_int(wi.w);
    const int i0 = pack & 63, i1 = (pack >> 6) & 63, i2 = (pack >> 12) & 63;
    const float4 pa = ((const float4*)(protos + (size_t)i0 * DIM + h * 256))[lane];
    const float4 pb = ((const float4*)(protos + (size_t)i1 * DIM + h * 256))[lane];
    const float4 pc = ((const float4*)(protos + (size_t)i2 * DIM + h * 256))[lane];
    float4 res;
    res.x = wi.x * pa.x + wi.y * pb.x + wi.z * pc.x;
    res.y = wi.x * pa.y + wi.y * pb.y + wi.z * pc.y;
    res.z = wi.x * pa.z + wi.y * pb.z + wi.z * pc.z;
    res.w = wi.x * pa.w + wi.y * pb.w + wi.z * pc.w;
    ((float4*)(out + (size_t)(row0 + r) * DIM + h * 256))[lane] = res;
  }
}

// ---------------------------------------------------------------------------
// Kernel 3: fp64 refine of compacted near-tie rows. One wave per row.
// lane = proto; coalesced ptw reads; 64-lane butterfly top-3.
// ---------------------------------------------------------------------------
__global__ __launch_bounds__(256) void refine_kernel(
    const float* __restrict__ query, const float* __restrict__ protos,
    const float* __restrict__ ptw, const double* __restrict__ inv64,
    const int* __restrict__ cnt, const int* __restrict__ list,
    float* __restrict__ out) {
  const int n = *cnt;
  const int lane = threadIdx.x & 63;
  const int gw = blockIdx.x * 4 + (threadIdx.x >> 6);

  for (int i = gw; i < n; i += RFB * 4) {
    const int row = list[i];
    const float* q = query + (size_t)row * DIM;
    double a0 = 0.0, a1 = 0.0, a2 = 0.0, a3 = 0.0;
    float qs = 0.f;
#pragma unroll 4
    for (int k = 0; k < DIM; k += 4) {
      const float4 qv = *(const float4*)(q + k);
      a0 = fma((double)qv.x, (double)ptw[(size_t)(k + 0) * NP + lane], a0);
      a1 = fma((double)qv.y, (double)ptw[(size_t)(k + 1) * NP + lane], a1);
      a2 = fma((double)qv.z, (double)ptw[(size_t)(k + 2) * NP + lane], a2);
      a3 = fma((double)qv.w, (double)ptw[(size_t)(k + 3) * NP + lane], a3);
      qs += qv.x * qv.x + qv.y * qv.y + qv.z * qv.z + qv.w * qv.w;
    }
    const double sim = (a0 + a1 + a2 + a3) * inv64[lane];

    double b0 = sim, b1 = -1e300, b2 = -1e300;
    int k0 = lane, k1 = 0, k2 = 0;
#pragma unroll
    for (int m = 1; m <= 32; m <<= 1) {
      const double p0 = __shfl_xor(b0, m), p1 = __shfl_xor(b1, m),
                   p2 = __shfl_xor(b2, m);
      const int q0 = __shfl_xor(k0, m), q1 = __shfl_xor(k1, m),
                q2 = __shfl_xor(k2, m);
      ins3d(p0, q0, b0, b1, b2, k0, k1, k2);
      ins3d(p1, q1, b0, b1, b2, k0, k1, k2);
      ins3d(p2, q2, b0, b1, b2, k0, k1, k2);
    }
    const double qi = 1.0 / fmax(sqrt((double)qs), 1e-12);
    const double s0 = b0 * qi, s1 = b1 * qi, s2 = b2 * qi;
    const double e1 = exp(s1 - s0), e2 = exp(s2 - s0);
    const double inv = 1.0 / (1.0 + e1 + e2);
    const double w0 = inv, w1 = e1 * inv, w2 = e2 * inv;
    const float* p0r = protos + (size_t)k0 * DIM;
    const float* p1r = protos + (size_t)k1 * DIM;
    const float* p2r = protos + (size_t)k2 * DIM;
#pragma unroll
    for (int u = 0; u < 2; ++u) {
      const int col = u * 256 + lane * 4;
      const float4 x = *(const float4*)(p0r + col);
      const float4 y = *(const float4*)(p1r + col);
      const float4 z = *(const float4*)(p2r + col);
      float4 res;
      res.x = (float)(w0 * x.x + w1 * y.x + w2 * z.x);
      res.y = (float)(w0 * x.y + w1 * y.y + w2 * z.y);
      res.z = (float)(w0 * x.z + w1 * y.z + w2 * z.z);
      res.w = (float)(w0 * x.w + w1 * y.w + w2 * z.w);
      *(float4*)(out + (size_t)row * DIM + col) = res;
    }
  }
}

extern "C" void kernel_launch(void* const* d_in, const int* in_sizes, int n_in,
                              void* d_out, int out_size, void* d_ws, size_t ws_size,
                              hipStream_t stream) {
  const float* query = (const float*)d_in[0];
  const float* protos = (const float*)d_in[1];
  float* out = (float*)d_out;
  float* ptw = (float*)((char*)d_ws + WS_PTRAW);
  double* inv64 = (double*)((char*)d_ws + WS_INV64);
  float* invpf = (float*)((char*)d_ws + WS_INVPF);
  int* cnt = (int*)((char*)d_ws + WS_CNT);
  int* list = (int*)((char*)d_ws + WS_LIST);

  const int nrows = in_sizes[0] / DIM;

  hipLaunchKernelGGL(prep_kernel, dim3(16), dim3(256), 0, stream,
                     protos, ptw, inv64, invpf, cnt);
  hipLaunchKernelGGL(sim_kernel, dim3(nrows / TRB), dim3(256), 0, stream,
                     query, protos, ptw, invpf, out, cnt, list);
  hipLaunchKernelGGL(refine_kernel, dim3(RFB), dim3(256), 0, stream,
                     query, protos, ptw, inv64, cnt, list, out);
}